// Round 4
// baseline (378.110 us; speedup 1.0000x reference)
//
#include <hip/hip_runtime.h>
#include <math.h>

// NetVLAD v4 — structural consolidation. B=32, D=512, K=64, N=3136.
// 5 launches: wprep (W hi/lo split + asum zero), G1 (logits+softmax+asum fused),
// G2 (vlad partials, BK=64, nsplit=4), combine, finalize (cninv+scale).
// G1: A-frags read directly from hi/lo ushort planes (no perms); x packed u32 + perm.
// G2: perm-based hi/lo repack; alpha bf16 (error ~2e-6 at output; thr 4.5e-4).

#define NN 3136
#define DD 512
#define KK 64
#define BB 32

typedef short bf16x8 __attribute__((ext_vector_type(8)));
typedef float f32x4  __attribute__((ext_vector_type(4)));

#define SEL_HI 0x05040100u   // low 16-bit halves of (a,b) pair
#define SEL_LO 0x07060302u   // high 16-bit halves

union FragU { uint4 u; bf16x8 f; };

static __device__ inline bf16x8 frag4(unsigned a, unsigned b, unsigned c, unsigned d) {
    FragU x; x.u = make_uint4(a, b, c, d); return x.f;
}

// pack fp32 -> u32 = hi_bf16 | lo_bf16<<16 (truncation split)
static __device__ inline unsigned pack_split(float f) {
    unsigned u = __float_as_uint(f);
    float hif = __uint_as_float(u & 0xFFFF0000u);
    unsigned lo = __float_as_uint(f - hif) >> 16;
    return (u >> 16) | (lo << 16);
}

static __device__ inline unsigned short bf16_rne(float f) {
    unsigned u = __float_as_uint(f);
    return (unsigned short)((u + 0x7FFFu + ((u >> 16) & 1u)) >> 16);
}

// ---------------------------------------------------------------- wprep
// Split conv_w [64][512] into hi/lo ushort planes; blocks 0..7 zero asum.
__global__ __launch_bounds__(256) void wprep_kernel(
    const float* __restrict__ w, unsigned short* __restrict__ wh,
    unsigned short* __restrict__ wl, float* __restrict__ asum)
{
    int i = blockIdx.x * 256 + threadIdx.x;   // < 32768
    unsigned pk = pack_split(w[i]);
    wh[i] = (unsigned short)(pk & 0xFFFFu);
    wl[i] = (unsigned short)(pk >> 16);
    if (blockIdx.x < 8) asum[blockIdx.x * 256 + threadIdx.x] = 0.f;
}

// ---------------------------------------------------------------- G1
// grid (25, 32), block 256 (4 waves). 64 clusters x 128 pixels, d-chunks of 32.
// Fused: logits (3-term split MFMA), softmax over K, alpha store (bf16),
// asum partial (shfl-reduce over 16 c-lanes + atomicAdd).
__global__ __launch_bounds__(256) void logits_softmax_mfma(
    const float* __restrict__ x,          // [B,D,N] fp32
    const unsigned short* __restrict__ wh,// [64][512] hi
    const unsigned short* __restrict__ wl,// [64][512] lo
    const float* __restrict__ bias,       // [64]
    unsigned short* __restrict__ alpha,   // [B,K,N] bf16
    float* __restrict__ asum)             // [B,K] fp32 (pre-zeroed)
{
    const int b  = blockIdx.y;
    const int n0 = blockIdx.x * 128;
    const int t  = threadIdx.x;
    const int lane = t & 63;
    const int wv   = t >> 6;
    const int c = lane & 15;
    const int q = lane >> 4;

    __shared__ __align__(16) unsigned xs[128][36];        // [n][d] packed u32
    __shared__ __align__(16) unsigned short wsh[64][40];  // [k][d] hi (80B rows)
    __shared__ __align__(16) unsigned short wsl[64][40];  // [k][d] lo

    f32x4 acc[4][2];
    #pragma unroll
    for (int mt = 0; mt < 4; mt++)
        #pragma unroll
        for (int r = 0; r < 4; r++) {
            float bv = bias[mt * 16 + q * 4 + r];
            acc[mt][0][r] = bv; acc[mt][1][r] = bv;
        }

    const float* xb = x + (size_t)b * DD * NN;
    const int n4 = t & 31;        // n offset within 32
    const int dr = t >> 5;        // 0..7 -> d col-group

    for (int dc = 0; dc < 16; dc++) {
        // stage x: scalar coalesced reads, pack+transpose into LDS
        #pragma unroll
        for (int j = 0; j < 4; j++) {
            int nn = n0 + n4 + 32 * j;
            if (nn > NN - 1) nn = NN - 1;
            unsigned pk[4];
            #pragma unroll
            for (int p = 0; p < 4; p++) {
                float v = xb[(size_t)(dc * 32 + dr * 4 + p) * NN + nn];
                pk[p] = pack_split(v);
            }
            *(uint4*)&xs[n4 + 32 * j][dr * 4] = make_uint4(pk[0], pk[1], pk[2], pk[3]);
        }
        // stage W planes: rows t>>2 (64), 4 lanes/row, uint4 (8 ushort) each
        {
            const int row = t >> 2, c8 = t & 3;
            const size_t off = (size_t)row * DD + dc * 32 + c8 * 8;
            *(uint4*)&wsh[row][c8 * 8] = *(const uint4*)&wh[off];
            *(uint4*)&wsl[row][c8 * 8] = *(const uint4*)&wl[off];
        }
        __syncthreads();

        // fragments: A direct b128 from planes; B via perm from packed xs
        bf16x8 ah[4], al[4], bh[2], bl[2];
        #pragma unroll
        for (int mt = 0; mt < 4; mt++) {
            ah[mt] = *(const bf16x8*)&wsh[mt * 16 + c][q * 8];
            al[mt] = *(const bf16x8*)&wsl[mt * 16 + c][q * 8];
        }
        #pragma unroll
        for (int nt = 0; nt < 2; nt++) {
            const int row = wv * 32 + nt * 16 + c;
            uint4 p0 = *(const uint4*)&xs[row][q * 8];
            uint4 p1 = *(const uint4*)&xs[row][q * 8 + 4];
            bh[nt] = frag4(__builtin_amdgcn_perm(p0.y, p0.x, SEL_HI),
                           __builtin_amdgcn_perm(p0.w, p0.z, SEL_HI),
                           __builtin_amdgcn_perm(p1.y, p1.x, SEL_HI),
                           __builtin_amdgcn_perm(p1.w, p1.z, SEL_HI));
            bl[nt] = frag4(__builtin_amdgcn_perm(p0.y, p0.x, SEL_LO),
                           __builtin_amdgcn_perm(p0.w, p0.z, SEL_LO),
                           __builtin_amdgcn_perm(p1.y, p1.x, SEL_LO),
                           __builtin_amdgcn_perm(p1.w, p1.z, SEL_LO));
        }
        #pragma unroll
        for (int mt = 0; mt < 4; mt++)
            #pragma unroll
            for (int nt = 0; nt < 2; nt++) {
                acc[mt][nt] = __builtin_amdgcn_mfma_f32_16x16x32_bf16(ah[mt], bh[nt], acc[mt][nt], 0, 0, 0);
                acc[mt][nt] = __builtin_amdgcn_mfma_f32_16x16x32_bf16(ah[mt], bl[nt], acc[mt][nt], 0, 0, 0);
                acc[mt][nt] = __builtin_amdgcn_mfma_f32_16x16x32_bf16(al[mt], bh[nt], acc[mt][nt], 0, 0, 0);
            }
        __syncthreads();
    }

    // fused softmax over 64 clusters + bf16 store + asum partials
    unsigned short* ab = alpha + (size_t)b * KK * NN;
    float sa[4][4];
    #pragma unroll
    for (int mt = 0; mt < 4; mt++)
        #pragma unroll
        for (int r = 0; r < 4; r++) sa[mt][r] = 0.f;

    #pragma unroll
    for (int nt = 0; nt < 2; nt++) {
        float mx = -1e30f;
        #pragma unroll
        for (int mt = 0; mt < 4; mt++)
            #pragma unroll
            for (int r = 0; r < 4; r++) mx = fmaxf(mx, acc[mt][nt][r]);
        mx = fmaxf(mx, __shfl_xor(mx, 16));
        mx = fmaxf(mx, __shfl_xor(mx, 32));
        float s = 0.f;
        #pragma unroll
        for (int mt = 0; mt < 4; mt++)
            #pragma unroll
            for (int r = 0; r < 4; r++) {
                float e = __expf(acc[mt][nt][r] - mx);
                acc[mt][nt][r] = e; s += e;
            }
        s += __shfl_xor(s, 16);
        s += __shfl_xor(s, 32);
        const float rinv = 1.0f / s;
        const int pix = n0 + wv * 32 + nt * 16 + c;
        const bool ok = pix < NN;
        #pragma unroll
        for (int mt = 0; mt < 4; mt++)
            #pragma unroll
            for (int r = 0; r < 4; r++) {
                unsigned short ub = bf16_rne(acc[mt][nt][r] * rinv);
                if (ok) {
                    ab[(size_t)(mt * 16 + q * 4 + r) * NN + pix] = ub;
                    // accumulate the DEQUANTIZED value so asum matches G2's bf16 alpha
                    sa[mt][r] += __uint_as_float((unsigned)ub << 16);
                }
            }
    }
    // reduce over the 16 c-lanes of each quad, then atomicAdd
    #pragma unroll
    for (int off = 1; off <= 8; off <<= 1)
        #pragma unroll
        for (int mt = 0; mt < 4; mt++)
            #pragma unroll
            for (int r = 0; r < 4; r++)
                sa[mt][r] += __shfl_xor(sa[mt][r], off);
    if (c == 0) {
        #pragma unroll
        for (int mt = 0; mt < 4; mt++)
            #pragma unroll
            for (int r = 0; r < 4; r++)
                atomicAdd(&asum[b * KK + mt * 16 + q * 4 + r], sa[mt][r]);
    }
}

// ---------------------------------------------------------------- G2
// grid (4 dtiles, 4 nsplit, 32). Block: 128 d x 64 k, n-chunks of 64 (2 K-steps).
__global__ __launch_bounds__(256) void vlad_mfma(
    const float* __restrict__ x,              // [B,D,N]
    const unsigned short* __restrict__ alpha, // [B,K,N] bf16
    float* __restrict__ pvlad)                // [4,B,D,K]
{
    const int dtile = blockIdx.x;   // 0..3
    const int ns    = blockIdx.y;   // 0..3
    const int b     = blockIdx.z;
    const int t     = threadIdx.x;
    const int lane = t & 63;
    const int wv   = t >> 6;
    const int c = lane & 15;
    const int q = lane >> 4;

    __shared__ __align__(16) unsigned short xh[128][72];  // [d][n] hi (144B rows)
    __shared__ __align__(16) unsigned short xl[128][72];
    __shared__ __align__(16) unsigned short as_[64][72];  // [k][n]

    f32x4 acc[2][4];
    #pragma unroll
    for (int mt = 0; mt < 2; mt++)
        #pragma unroll
        for (int nt = 0; nt < 4; nt++)
            #pragma unroll
            for (int r = 0; r < 4; r++) acc[mt][nt][r] = 0.f;

    const float* xb = x + ((size_t)b * DD + dtile * 128) * NN;
    const int nq = t & 15, dr2 = t >> 4;     // x staging coords
    const int arow = t >> 2, ac = t & 3;     // alpha staging coords

    const int nchunk = 784;                  // NN/4
    for (int cc = 0; cc < 13; cc++) {        // 13*64 >= 784
        const int nb = ns * nchunk + cc * 64;
        const int nvalid = min(64, nchunk - cc * 64);   // 64 or 16 (mult of 16)
        // stage x: thread covers d = dr2 + 16p, n = nb + nq*4..+3
        #pragma unroll
        for (int p = 0; p < 8; p++) {
            const int d = dr2 + p * 16;
            uint2 h = make_uint2(0u, 0u), l = make_uint2(0u, 0u);
            if (nq * 4 < nvalid) {
                float4 v = *(const float4*)&xb[(size_t)d * NN + nb + nq * 4];
                unsigned pk0 = pack_split(v.x), pk1 = pack_split(v.y);
                unsigned pk2 = pack_split(v.z), pk3 = pack_split(v.w);
                h.x = __builtin_amdgcn_perm(pk1, pk0, SEL_HI);
                h.y = __builtin_amdgcn_perm(pk3, pk2, SEL_HI);
                l.x = __builtin_amdgcn_perm(pk1, pk0, SEL_LO);
                l.y = __builtin_amdgcn_perm(pk3, pk2, SEL_LO);
            }
            *(uint2*)&xh[d][nq * 4] = h;
            *(uint2*)&xl[d][nq * 4] = l;
        }
        // stage alpha: row arow (64), 4 lanes/row, 2 uint4 (16 ushort) each
        #pragma unroll
        for (int j = 0; j < 2; j++) {
            const int col = ac * 16 + j * 8;
            uint4 v = make_uint4(0u, 0u, 0u, 0u);
            if (col < nvalid)
                v = *(const uint4*)&alpha[((size_t)b * KK + arow) * NN + nb + col];
            *(uint4*)&as_[arow][col] = v;
        }
        __syncthreads();

        #pragma unroll
        for (int ks = 0; ks < 2; ks++) {
            const int colb = ks * 32 + q * 8;
            bf16x8 ah[2], al2[2], bh[4];
            #pragma unroll
            for (int mt = 0; mt < 2; mt++) {
                const int row = wv * 32 + mt * 16 + c;
                ah[mt]  = *(const bf16x8*)&xh[row][colb];
                al2[mt] = *(const bf16x8*)&xl[row][colb];
            }
            #pragma unroll
            for (int nt = 0; nt < 4; nt++)
                bh[nt] = *(const bf16x8*)&as_[nt * 16 + c][colb];
            #pragma unroll
            for (int mt = 0; mt < 2; mt++)
                #pragma unroll
                for (int nt = 0; nt < 4; nt++) {
                    acc[mt][nt] = __builtin_amdgcn_mfma_f32_16x16x32_bf16(ah[mt],  bh[nt], acc[mt][nt], 0, 0, 0);
                    acc[mt][nt] = __builtin_amdgcn_mfma_f32_16x16x32_bf16(al2[mt], bh[nt], acc[mt][nt], 0, 0, 0);
                }
        }
        __syncthreads();
    }

    float* pv = pvlad + (((size_t)ns * BB + b) * DD + dtile * 128 + wv * 32) * KK;
    #pragma unroll
    for (int mt = 0; mt < 2; mt++)
        #pragma unroll
        for (int r = 0; r < 4; r++) {
            const int dl = mt * 16 + q * 4 + r;
            #pragma unroll
            for (int nt = 0; nt < 4; nt++)
                pv[(size_t)dl * KK + nt * 16 + c] = acc[mt][nt][r];
        }
}

// ---------------------------------------------------------------- combine
// grid (4, 32), block 256: sum 4 partials, subtract centers*asum, write vlad + psq.
__global__ __launch_bounds__(256) void combine_norm(
    const float* __restrict__ pvlad, const float* __restrict__ centers,
    const float* __restrict__ asum, float* __restrict__ vlad,
    float* __restrict__ psq)
{
    const int dchunk = blockIdx.x;
    const int b = blockIdx.y;
    const int t = threadIdx.x;
    const int k4 = (t & 15) * 4;
    const int dq = t >> 4;          // 0..15
    const float4 av = *(const float4*)&asum[b * KK + k4];
    float sqx = 0.f, sqy = 0.f, sqz = 0.f, sqw = 0.f;
    for (int i = 0; i < 8; i++) {
        const int d = dchunk * 128 + i * 16 + dq;
        float vx = 0.f, vy = 0.f, vz = 0.f, vw = 0.f;
        #pragma unroll
        for (int ns = 0; ns < 4; ns++) {
            const float4 p = *(const float4*)&pvlad[(((size_t)ns * BB + b) * DD + d) * KK + k4];
            vx += p.x; vy += p.y; vz += p.z; vw += p.w;
        }
        const float4 cv = *(const float4*)&centers[d * KK + k4];
        vx -= cv.x * av.x; vy -= cv.y * av.y; vz -= cv.z * av.z; vw -= cv.w * av.w;
        *(float4*)&vlad[((size_t)b * DD + d) * KK + k4] = make_float4(vx, vy, vz, vw);
        sqx = fmaf(vx, vx, sqx); sqy = fmaf(vy, vy, sqy);
        sqz = fmaf(vz, vz, sqz); sqw = fmaf(vw, vw, sqw);
    }
    __shared__ float red[16][64];
    red[dq][k4 + 0] = sqx; red[dq][k4 + 1] = sqy;
    red[dq][k4 + 2] = sqz; red[dq][k4 + 3] = sqw;
    __syncthreads();
    if (t < 64) {
        float s = 0.f;
        #pragma unroll
        for (int qq = 0; qq < 16; qq++) s += red[qq][t];
        psq[(b * 4 + dchunk) * 64 + t] = s;
    }
}

// ---------------------------------------------------------------- finalize
// grid (4, 32), block 256: cninv from psq (in LDS), scale vlad -> out.
__global__ __launch_bounds__(256) void finalize_kernel(
    const float* __restrict__ psq, const float* __restrict__ vlad,
    float* __restrict__ out)
{
    const int dchunk = blockIdx.x;
    const int b = blockIdx.y;
    const int t = threadIdx.x;
    __shared__ float cn[64];
    if (t < 64) {
        float s = psq[b * 256 + t] + psq[b * 256 + 64 + t]
                + psq[b * 256 + 128 + t] + psq[b * 256 + 192 + t];
        cn[t] = 1.0f / (sqrtf(s) * 8.0f);   // global norm of K unit cols == 8
    }
    __syncthreads();
    const int k4 = (t & 15) * 4;
    const int dq = t >> 4;
    const float4 cv = *(const float4*)&cn[k4];
    #pragma unroll
    for (int i = 0; i < 8; i++) {
        const size_t idx = ((size_t)b * DD + dchunk * 128 + i * 16 + dq) * KK + k4;
        float4 v = *(const float4*)&vlad[idx];
        *(float4*)&out[idx] = make_float4(v.x * cv.x, v.y * cv.y, v.z * cv.z, v.w * cv.w);
    }
}

// ---------------------------------------------------------------- launch
extern "C" void kernel_launch(void* const* d_in, const int* in_sizes, int n_in,
                              void* d_out, int out_size, void* d_ws, size_t ws_size,
                              hipStream_t stream) {
    const float* x       = (const float*)d_in[0];
    const float* conv_w  = (const float*)d_in[1];
    const float* conv_b  = (const float*)d_in[2];
    const float* centers = (const float*)d_in[3];
    float* out = (float*)d_out;

    unsigned short* wh    = (unsigned short*)d_ws;                   // 32768 ushort
    unsigned short* wl    = wh + 32768;                              // 32768 ushort
    unsigned short* alpha = wl + 32768;                              // 6,422,528 bf16
    float* asum  = (float*)(alpha + (size_t)BB * KK * NN);           // 2048
    float* vlad  = asum + 2048;                                      // 1,048,576
    float* psq   = vlad + 1048576;                                   // 8192
    float* pvlad = psq + 8192;                                       // 4 * 1,048,576

    wprep_kernel       <<<dim3(128),        dim3(256), 0, stream>>>(conv_w, wh, wl, asum);
    logits_softmax_mfma<<<dim3(25, BB),     dim3(256), 0, stream>>>(x, wh, wl, conv_b, alpha, asum);
    vlad_mfma          <<<dim3(4, 4, BB),   dim3(256), 0, stream>>>(x, alpha, pvlad);
    combine_norm       <<<dim3(4, BB),      dim3(256), 0, stream>>>(pvlad, centers, asum, vlad, psq);
    finalize_kernel    <<<dim3(4, BB),      dim3(256), 0, stream>>>(psq, vlad, out);
}

// Round 5
// 369.247 us; speedup vs baseline: 1.0240x; 1.0240x over previous
//
#include <hip/hip_runtime.h>
#include <math.h>

// NetVLAD v5 — register-prefetch pipelining + atomic vlad accumulation.
// B=32, D=512, K=64, N=3136.
// wprep: W hi/lo split + zero vlad/asum.
// G1: logits+softmax+asum fused, grid(25,32); per-dc global loads prefetched
//     into registers one iteration ahead (overlap with MFMA section).
// G2: vlad accumulated via atomicAdd into pre-zeroed vlad (no pvlad round-trip),
//     grid(4,4,32), BK=64, register prefetch.
// combine: vlad -= centers*asum (in place) + per-column sq-sums.
// finalize: cninv + scale -> out.

#define NN 3136
#define DD 512
#define KK 64
#define BB 32

typedef short bf16x8 __attribute__((ext_vector_type(8)));
typedef float f32x4  __attribute__((ext_vector_type(4)));

#define SEL_HI   0x05040100u   // (a_low16<<16) | b_low16
#define SEL_LO   0x07060302u   // (a_high16<<16) | b_high16
#define SEL_PACK 0x07060302u   // a=lo_f32, b=x_f32 -> (lo_hi16<<16) | x_hi16

union FragU { uint4 u; bf16x8 f; };

static __device__ inline bf16x8 frag4(unsigned a, unsigned b, unsigned c, unsigned d) {
    FragU x; x.u = make_uint4(a, b, c, d); return x.f;
}

static __device__ inline unsigned short bf16_rne(float f) {
    unsigned u = __float_as_uint(f);
    return (unsigned short)((u + 0x7FFFu + ((u >> 16) & 1u)) >> 16);
}

// ---------------------------------------------------------------- wprep
// grid 1024: W split (i<32768), zero vlad (1M floats), zero asum.
__global__ __launch_bounds__(256) void wprep_kernel(
    const float* __restrict__ w, unsigned short* __restrict__ wh,
    unsigned short* __restrict__ wl, float* __restrict__ asum,
    float* __restrict__ vlad)
{
    const int i = blockIdx.x * 256 + threadIdx.x;    // < 262144
    if (i < 32768) {
        float v = w[i];
        float hif = __uint_as_float(__float_as_uint(v) & 0xFFFF0000u);
        float lof = v - hif;
        wh[i] = (unsigned short)(__float_as_uint(v) >> 16);
        wl[i] = (unsigned short)(__float_as_uint(lof) >> 16);
    }
    *(float4*)&vlad[(size_t)i * 4] = make_float4(0.f, 0.f, 0.f, 0.f);
    if (i < 2048) asum[i] = 0.f;
}

// ---------------------------------------------------------------- G1
// grid (25, 32), block 256 (4 waves). 64 clusters x 128 pixels, d-chunks of 32.
// Register prefetch: loads for dc+1 issued before the barriers of dc.
__global__ __launch_bounds__(256) void logits_softmax_mfma(
    const float* __restrict__ x,          // [B,D,N] fp32
    const unsigned short* __restrict__ wh,// [64][512] hi
    const unsigned short* __restrict__ wl,// [64][512] lo
    const float* __restrict__ bias,       // [64]
    unsigned short* __restrict__ alpha,   // [B,K,N] bf16
    float* __restrict__ asum)             // [B,K] fp32 (pre-zeroed)
{
    const int b  = blockIdx.y;
    const int n0 = blockIdx.x * 128;
    const int t  = threadIdx.x;
    const int lane = t & 63;
    const int wv   = t >> 6;
    const int c = lane & 15;
    const int q = lane >> 4;

    __shared__ __align__(16) unsigned xs[128][36];        // [n][d] packed u32
    __shared__ __align__(16) unsigned short wsh[64][40];  // [k][d] hi
    __shared__ __align__(16) unsigned short wsl[64][40];  // [k][d] lo

    f32x4 acc[4][2];
    #pragma unroll
    for (int mt = 0; mt < 4; mt++)
        #pragma unroll
        for (int r = 0; r < 4; r++) {
            float bv = bias[mt * 16 + q * 4 + r];
            acc[mt][0][r] = bv; acc[mt][1][r] = bv;
        }

    const float* xb = x + (size_t)b * DD * NN;
    const int n4 = t & 31;        // n offset within 32
    const int dr = t >> 5;        // 0..7 -> d col-group
    const int wrow = t >> 2, wc8 = t & 3;

    // ---- prefetch dc=0
    float xr[16];
    uint4 wrh, wrl;
    {
        #pragma unroll
        for (int j = 0; j < 4; j++) {
            int nn = n0 + n4 + 32 * j;
            if (nn > NN - 1) nn = NN - 1;
            #pragma unroll
            for (int p = 0; p < 4; p++)
                xr[j * 4 + p] = xb[(size_t)(dr * 4 + p) * NN + nn];
        }
        wrh = *(const uint4*)&wh[(size_t)wrow * DD + wc8 * 8];
        wrl = *(const uint4*)&wl[(size_t)wrow * DD + wc8 * 8];
    }

    for (int dc = 0; dc < 16; dc++) {
        // pack current regs (frees xr for the next prefetch)
        uint4 xp[4];
        #pragma unroll
        for (int j = 0; j < 4; j++) {
            unsigned pk[4];
            #pragma unroll
            for (int p = 0; p < 4; p++) {
                float v = xr[j * 4 + p];
                float hif = __uint_as_float(__float_as_uint(v) & 0xFFFF0000u);
                float lof = v - hif;
                pk[p] = __builtin_amdgcn_perm(__float_as_uint(lof), __float_as_uint(v), SEL_PACK);
            }
            xp[j] = make_uint4(pk[0], pk[1], pk[2], pk[3]);
        }
        uint4 wch = wrh, wcl = wrl;

        // prefetch dc+1 (in flight across the MFMA section below)
        if (dc < 15) {
            const int d0 = (dc + 1) * 32;
            #pragma unroll
            for (int j = 0; j < 4; j++) {
                int nn = n0 + n4 + 32 * j;
                if (nn > NN - 1) nn = NN - 1;
                #pragma unroll
                for (int p = 0; p < 4; p++)
                    xr[j * 4 + p] = xb[(size_t)(d0 + dr * 4 + p) * NN + nn];
            }
            wrh = *(const uint4*)&wh[(size_t)wrow * DD + d0 + wc8 * 8];
            wrl = *(const uint4*)&wl[(size_t)wrow * DD + d0 + wc8 * 8];
        }

        __syncthreads();   // prev LDS consumers done
        #pragma unroll
        for (int j = 0; j < 4; j++)
            *(uint4*)&xs[n4 + 32 * j][dr * 4] = xp[j];
        *(uint4*)&wsh[wrow][wc8 * 8] = wch;
        *(uint4*)&wsl[wrow][wc8 * 8] = wcl;
        __syncthreads();   // LDS visible

        // fragments: A direct b128 from planes; B via perm from packed xs
        bf16x8 ah[4], al[4], bh[2], bl[2];
        #pragma unroll
        for (int mt = 0; mt < 4; mt++) {
            ah[mt] = *(const bf16x8*)&wsh[mt * 16 + c][q * 8];
            al[mt] = *(const bf16x8*)&wsl[mt * 16 + c][q * 8];
        }
        #pragma unroll
        for (int nt = 0; nt < 2; nt++) {
            const int row = wv * 32 + nt * 16 + c;
            uint4 p0 = *(const uint4*)&xs[row][q * 8];
            uint4 p1 = *(const uint4*)&xs[row][q * 8 + 4];
            bh[nt] = frag4(__builtin_amdgcn_perm(p0.y, p0.x, SEL_HI),
                           __builtin_amdgcn_perm(p0.w, p0.z, SEL_HI),
                           __builtin_amdgcn_perm(p1.y, p1.x, SEL_HI),
                           __builtin_amdgcn_perm(p1.w, p1.z, SEL_HI));
            bl[nt] = frag4(__builtin_amdgcn_perm(p0.y, p0.x, SEL_LO),
                           __builtin_amdgcn_perm(p0.w, p0.z, SEL_LO),
                           __builtin_amdgcn_perm(p1.y, p1.x, SEL_LO),
                           __builtin_amdgcn_perm(p1.w, p1.z, SEL_LO));
        }
        #pragma unroll
        for (int mt = 0; mt < 4; mt++)
            #pragma unroll
            for (int nt = 0; nt < 2; nt++) {
                acc[mt][nt] = __builtin_amdgcn_mfma_f32_16x16x32_bf16(ah[mt], bh[nt], acc[mt][nt], 0, 0, 0);
                acc[mt][nt] = __builtin_amdgcn_mfma_f32_16x16x32_bf16(ah[mt], bl[nt], acc[mt][nt], 0, 0, 0);
                acc[mt][nt] = __builtin_amdgcn_mfma_f32_16x16x32_bf16(al[mt], bh[nt], acc[mt][nt], 0, 0, 0);
            }
    }

    // fused softmax over 64 clusters + bf16 store + asum partials
    unsigned short* ab = alpha + (size_t)b * KK * NN;
    float sa[4][4];
    #pragma unroll
    for (int mt = 0; mt < 4; mt++)
        #pragma unroll
        for (int r = 0; r < 4; r++) sa[mt][r] = 0.f;

    #pragma unroll
    for (int nt = 0; nt < 2; nt++) {
        float mx = -1e30f;
        #pragma unroll
        for (int mt = 0; mt < 4; mt++)
            #pragma unroll
            for (int r = 0; r < 4; r++) mx = fmaxf(mx, acc[mt][nt][r]);
        mx = fmaxf(mx, __shfl_xor(mx, 16));
        mx = fmaxf(mx, __shfl_xor(mx, 32));
        float s = 0.f;
        #pragma unroll
        for (int mt = 0; mt < 4; mt++)
            #pragma unroll
            for (int r = 0; r < 4; r++) {
                float e = __expf(acc[mt][nt][r] - mx);
                acc[mt][nt][r] = e; s += e;
            }
        s += __shfl_xor(s, 16);
        s += __shfl_xor(s, 32);
        const float rinv = 1.0f / s;
        const int pix = n0 + wv * 32 + nt * 16 + c;
        const bool ok = pix < NN;
        #pragma unroll
        for (int mt = 0; mt < 4; mt++)
            #pragma unroll
            for (int r = 0; r < 4; r++) {
                unsigned short ub = bf16_rne(acc[mt][nt][r] * rinv);
                if (ok) {
                    ab[(size_t)(mt * 16 + q * 4 + r) * NN + pix] = ub;
                    sa[mt][r] += __uint_as_float((unsigned)ub << 16);  // dequantized
                }
            }
    }
    #pragma unroll
    for (int off = 1; off <= 8; off <<= 1)
        #pragma unroll
        for (int mt = 0; mt < 4; mt++)
            #pragma unroll
            for (int r = 0; r < 4; r++)
                sa[mt][r] += __shfl_xor(sa[mt][r], off);
    if (c == 0) {
        #pragma unroll
        for (int mt = 0; mt < 4; mt++)
            #pragma unroll
            for (int r = 0; r < 4; r++)
                atomicAdd(&asum[b * KK + mt * 16 + q * 4 + r], sa[mt][r]);
    }
}

// ---------------------------------------------------------------- G2
// grid (4 dtiles, 4 nsplit, 32). Block: 128 d x 64 k, n-chunks of 64.
// Epilogue: atomicAdd into pre-zeroed vlad (no pvlad).
__global__ __launch_bounds__(256) void vlad_mfma(
    const float* __restrict__ x,              // [B,D,N]
    const unsigned short* __restrict__ alpha, // [B,K,N] bf16
    float* __restrict__ vlad)                 // [B,D,K] (zeroed)
{
    const int dtile = blockIdx.x;   // 0..3
    const int ns    = blockIdx.y;   // 0..3
    const int b     = blockIdx.z;
    const int t     = threadIdx.x;
    const int lane = t & 63;
    const int wv   = t >> 6;
    const int c = lane & 15;
    const int q = lane >> 4;

    __shared__ __align__(16) unsigned short xh[128][72];
    __shared__ __align__(16) unsigned short xl[128][72];
    __shared__ __align__(16) unsigned short as_[64][72];

    f32x4 acc[2][4];
    #pragma unroll
    for (int mt = 0; mt < 2; mt++)
        #pragma unroll
        for (int nt = 0; nt < 4; nt++)
            #pragma unroll
            for (int r = 0; r < 4; r++) acc[mt][nt][r] = 0.f;

    const float* xb = x + ((size_t)b * DD + dtile * 128) * NN;
    const int nq = t & 15, dr2 = t >> 4;
    const int arow = t >> 2, ac = t & 3;
    const int nchunk = 784;

    float4 xr[8];
    uint4  ar[2];
    // ---- prefetch cc=0
    {
        const int nb = ns * nchunk;
        #pragma unroll
        for (int p = 0; p < 8; p++)
            xr[p] = *(const float4*)&xb[(size_t)(dr2 + p * 16) * NN + nb + nq * 4];
        #pragma unroll
        for (int j = 0; j < 2; j++)
            ar[j] = *(const uint4*)&alpha[((size_t)b * KK + arow) * NN + nb + ac * 16 + j * 8];
    }

    for (int cc = 0; cc < 13; cc++) {
        // pack current regs
        uint2 ph[8], pl[8];
        #pragma unroll
        for (int p = 0; p < 8; p++) {
            float4 v = xr[p];
            unsigned ux = __float_as_uint(v.x), uy = __float_as_uint(v.y);
            unsigned uz = __float_as_uint(v.z), uw = __float_as_uint(v.w);
            ph[p].x = __builtin_amdgcn_perm(uy, ux, SEL_LO);
            ph[p].y = __builtin_amdgcn_perm(uw, uz, SEL_LO);
            float lx = v.x - __uint_as_float(ux & 0xFFFF0000u);
            float ly = v.y - __uint_as_float(uy & 0xFFFF0000u);
            float lz = v.z - __uint_as_float(uz & 0xFFFF0000u);
            float lw = v.w - __uint_as_float(uw & 0xFFFF0000u);
            pl[p].x = __builtin_amdgcn_perm(__float_as_uint(ly), __float_as_uint(lx), SEL_LO);
            pl[p].y = __builtin_amdgcn_perm(__float_as_uint(lw), __float_as_uint(lz), SEL_LO);
        }
        uint4 ac_[2] = { ar[0], ar[1] };

        // prefetch cc+1
        if (cc < 12) {
            const int nb = ns * nchunk + (cc + 1) * 64;
            const int nvalid = min(64, nchunk - (cc + 1) * 64);   // 64 or 16
            #pragma unroll
            for (int p = 0; p < 8; p++) {
                xr[p] = make_float4(0.f, 0.f, 0.f, 0.f);
                if (nq * 4 < nvalid)
                    xr[p] = *(const float4*)&xb[(size_t)(dr2 + p * 16) * NN + nb + nq * 4];
            }
            #pragma unroll
            for (int j = 0; j < 2; j++) {
                const int col = ac * 16 + j * 8;
                ar[j] = make_uint4(0u, 0u, 0u, 0u);
                if (col < nvalid)
                    ar[j] = *(const uint4*)&alpha[((size_t)b * KK + arow) * NN + nb + col];
            }
        }

        __syncthreads();
        #pragma unroll
        for (int p = 0; p < 8; p++) {
            *(uint2*)&xh[dr2 + p * 16][nq * 4] = ph[p];
            *(uint2*)&xl[dr2 + p * 16][nq * 4] = pl[p];
        }
        #pragma unroll
        for (int j = 0; j < 2; j++)
            *(uint4*)&as_[arow][ac * 16 + j * 8] = ac_[j];
        __syncthreads();

        #pragma unroll
        for (int ks = 0; ks < 2; ks++) {
            const int colb = ks * 32 + q * 8;
            bf16x8 ah[2], al2[2], bh[4];
            #pragma unroll
            for (int mt = 0; mt < 2; mt++) {
                const int row = wv * 32 + mt * 16 + c;
                ah[mt]  = *(const bf16x8*)&xh[row][colb];
                al2[mt] = *(const bf16x8*)&xl[row][colb];
            }
            #pragma unroll
            for (int nt = 0; nt < 4; nt++)
                bh[nt] = *(const bf16x8*)&as_[nt * 16 + c][colb];
            #pragma unroll
            for (int mt = 0; mt < 2; mt++)
                #pragma unroll
                for (int nt = 0; nt < 4; nt++) {
                    acc[mt][nt] = __builtin_amdgcn_mfma_f32_16x16x32_bf16(ah[mt],  bh[nt], acc[mt][nt], 0, 0, 0);
                    acc[mt][nt] = __builtin_amdgcn_mfma_f32_16x16x32_bf16(al2[mt], bh[nt], acc[mt][nt], 0, 0, 0);
                }
        }
    }

    float* pv = vlad + ((size_t)b * DD + dtile * 128 + wv * 32) * KK;
    #pragma unroll
    for (int mt = 0; mt < 2; mt++)
        #pragma unroll
        for (int r = 0; r < 4; r++) {
            const int dl = mt * 16 + q * 4 + r;
            #pragma unroll
            for (int nt = 0; nt < 4; nt++)
                atomicAdd(&pv[(size_t)dl * KK + nt * 16 + c], acc[mt][nt][r]);
        }
}

// ---------------------------------------------------------------- combine
// grid (4, 32): vlad -= centers*asum (in place), psq partial sq-sums.
__global__ __launch_bounds__(256) void combine_norm(
    const float* __restrict__ centers, const float* __restrict__ asum,
    float* __restrict__ vlad, float* __restrict__ psq)
{
    const int dchunk = blockIdx.x;
    const int b = blockIdx.y;
    const int t = threadIdx.x;
    const int k4 = (t & 15) * 4;
    const int dq = t >> 4;          // 0..15
    const float4 av = *(const float4*)&asum[b * KK + k4];
    float sqx = 0.f, sqy = 0.f, sqz = 0.f, sqw = 0.f;
    for (int i = 0; i < 8; i++) {
        const int d = dchunk * 128 + i * 16 + dq;
        const size_t idx = ((size_t)b * DD + d) * KK + k4;
        float4 p = *(const float4*)&vlad[idx];
        const float4 cv = *(const float4*)&centers[d * KK + k4];
        float vx = p.x - cv.x * av.x, vy = p.y - cv.y * av.y;
        float vz = p.z - cv.z * av.z, vw = p.w - cv.w * av.w;
        *(float4*)&vlad[idx] = make_float4(vx, vy, vz, vw);
        sqx = fmaf(vx, vx, sqx); sqy = fmaf(vy, vy, sqy);
        sqz = fmaf(vz, vz, sqz); sqw = fmaf(vw, vw, sqw);
    }
    __shared__ float red[16][64];
    red[dq][k4 + 0] = sqx; red[dq][k4 + 1] = sqy;
    red[dq][k4 + 2] = sqz; red[dq][k4 + 3] = sqw;
    __syncthreads();
    if (t < 64) {
        float s = 0.f;
        #pragma unroll
        for (int qq = 0; qq < 16; qq++) s += red[qq][t];
        psq[(b * 4 + dchunk) * 64 + t] = s;
    }
}

// ---------------------------------------------------------------- finalize
__global__ __launch_bounds__(256) void finalize_kernel(
    const float* __restrict__ psq, const float* __restrict__ vlad,
    float* __restrict__ out)
{
    const int dchunk = blockIdx.x;
    const int b = blockIdx.y;
    const int t = threadIdx.x;
    __shared__ float cn[64];
    if (t < 64) {
        float s = psq[b * 256 + t] + psq[b * 256 + 64 + t]
                + psq[b * 256 + 128 + t] + psq[b * 256 + 192 + t];
        cn[t] = 1.0f / (sqrtf(s) * 8.0f);   // global norm of K unit cols == 8
    }
    __syncthreads();
    const int k4 = (t & 15) * 4;
    const int dq = t >> 4;
    const float4 cv = *(const float4*)&cn[k4];
    #pragma unroll
    for (int i = 0; i < 8; i++) {
        const size_t idx = ((size_t)b * DD + dchunk * 128 + i * 16 + dq) * KK + k4;
        float4 v = *(const float4*)&vlad[idx];
        *(float4*)&out[idx] = make_float4(v.x * cv.x, v.y * cv.y, v.z * cv.z, v.w * cv.w);
    }
}

// ---------------------------------------------------------------- launch
extern "C" void kernel_launch(void* const* d_in, const int* in_sizes, int n_in,
                              void* d_out, int out_size, void* d_ws, size_t ws_size,
                              hipStream_t stream) {
    const float* x       = (const float*)d_in[0];
    const float* conv_w  = (const float*)d_in[1];
    const float* conv_b  = (const float*)d_in[2];
    const float* centers = (const float*)d_in[3];
    float* out = (float*)d_out;

    unsigned short* wh    = (unsigned short*)d_ws;                   // 32768 ushort
    unsigned short* wl    = wh + 32768;                              // 32768 ushort
    unsigned short* alpha = wl + 32768;                              // 6,422,528 bf16
    float* asum  = (float*)(alpha + (size_t)BB * KK * NN);           // 2048
    float* vlad  = asum + 2048;                                      // 1,048,576
    float* psq   = vlad + 1048576;                                   // 8192

    wprep_kernel       <<<dim3(1024),       dim3(256), 0, stream>>>(conv_w, wh, wl, asum, vlad);
    logits_softmax_mfma<<<dim3(25, BB),     dim3(256), 0, stream>>>(x, wh, wl, conv_b, alpha, asum);
    vlad_mfma          <<<dim3(4, 4, BB),   dim3(256), 0, stream>>>(x, alpha, vlad);
    combine_norm       <<<dim3(4, BB),      dim3(256), 0, stream>>>(centers, asum, vlad, psq);
    finalize_kernel    <<<dim3(4, BB),      dim3(256), 0, stream>>>(psq, vlad, out);
}